// Round 13
// baseline (286.648 us; speedup 1.0000x reference)
//
#include <hip/hip_runtime.h>
#include <hip/hip_cooperative_groups.h>

namespace cg = cooperative_groups;

#define NN 4096
#define NE 32768
#define PED 16
#define HID 128
#define CW 16          // columns per block slice
#define NCHUNK 64      // NN/64 rows per chunk
#define THREADS 1024   // 16 waves
#define PASSES 4       // NCHUNK / 16 waves

typedef _Float16 h_t;
typedef _Float16 h8 __attribute__((ext_vector_type(8)));
typedef unsigned long long u64;

// LDS BYTE offset for SORTED slot p (row rowperm[p]).
// 128-B window = 4 slots x 32 B (lo half 16 B + hi half 16 B = 16 fp16 cols).
// granule g = ((p&3)<<1) | window-parity; hi half = ^16.
__device__ __forceinline__ int xp(int p) {
  int g = ((p & 3) << 1) | ((p >> 2) & 1);
  return ((p >> 2) << 7) | (g << 4);
}

// ---- ALL preprocessing in one cooperative dispatch: 64 blocks x 512 = NE
// threads; each phase at its natural parallelism, separated by grid.sync ----
__global__ __launch_bounds__(512)
void prep_coop(const int* __restrict__ senders, const int* __restrict__ receivers,
               float* __restrict__ dinv, int* __restrict__ sortpos,
               int* __restrict__ rowperm, int* __restrict__ indeg,
               int* __restrict__ outdeg, int* __restrict__ fillc,
               int* __restrict__ chunk_off, int* __restrict__ chunk_len,
               int2* __restrict__ esrc, int2* __restrict__ edst) {
  cg::grid_group grid = cg::this_grid();
  __shared__ int ld_d[NN];  // 16 KB (block 0, phase B)
  __shared__ int rp[NN];    // 16 KB (block 0, phase B)
  __shared__ int hist[64], hbase[64];
  int tid = blockIdx.x * 512 + threadIdx.x;  // 0..NE-1 exactly

  // phase 0: zero counters
  if (tid < NN) { outdeg[tid] = 0; indeg[tid] = 0; fillc[tid] = 0; }
  grid.sync();

  // phase A: degree count (one edge per thread, device-scope atomics)
  atomicAdd(&outdeg[senders[tid]], 1);
  atomicAdd(&indeg[receivers[tid]], 1);
  grid.sync();

  // phase B: row-level sort (block 0 only; LDS histogram + counting sort)
  if (blockIdx.x == 0) {
    int t = threadIdx.x;
    if (t < 64) hist[t] = 0;
    __syncthreads();
    for (int r = t; r < NN; r += 512) {
      int od = outdeg[r]; if (od < 1) od = 1;
      dinv[r] = 1.0f / (float)od;
      int d = indeg[r]; if (d > 63) d = 63;
      ld_d[r] = d;
      indeg[r] = d;  // clamped, consumed by phase D
      atomicAdd(&hist[d], 1);
    }
    __syncthreads();
    if (t == 0) { int acc = 0; for (int i = 0; i < 64; ++i) { hbase[i] = acc; acc += hist[i]; } }
    __syncthreads();
    for (int r = t; r < NN; r += 512) {
      int pos = atomicAdd(&hbase[ld_d[r]], 1);
      rp[pos] = r;
      sortpos[r] = pos;
    }
    __syncthreads();
    for (int i = t; i < NN; i += 512) rowperm[i] = rp[i];
    if (t < NCHUNK) {
      int m = 0;
      for (int i = 0; i < 64; ++i) { int d = ld_d[rp[(t << 6) + i]]; if (d > m) m = d; }
      chunk_len[t] = (m + 1) & ~1;  // even, <= 64
    }
    __syncthreads();
    if (t == 0) {
      int acc = 0;
      for (int c = 0; c < NCHUNK; ++c) { chunk_off[c] = acc; acc += chunk_len[c] << 6; }
      chunk_off[NCHUNK] = acc;
    }
  }
  __threadfence();
  grid.sync();

  // phase C: fill lane-major ELL (one edge per thread)
  {
    int r = receivers[tid], s = senders[tid];
    int p = sortpos[r];
    int ts = atomicAdd(&fillc[r], 1);
    if (ts < 64) {
      int slot = chunk_off[p >> 6] + (ts << 6) + (p & 63);
      esrc[slot] = make_int2(xp(sortpos[s]), __float_as_int(dinv[s]));
    }
  }
  __threadfence();
  grid.sync();

  // phase D: prefetch-tail zero + greedy bipartite edge-coloring (512 tracks)
  {
    int total = chunk_off[NCHUNK];
    if (tid >= 512 && tid < 512 + 2048) edst[total + (tid - 512)] = make_int2(0, 0);
  }
  if (tid < NCHUNK * 8) {
    int c = tid >> 3;
    int trk = tid & 7;
    int base = chunk_off[c];
    int len = chunk_len[c];   // <= 64
    int l0 = trk << 3;
    int d[8];
    u64 freeL[8];
    int dmax = 0;
#pragma unroll
    for (int j = 0; j < 8; ++j) {
      int dd = indeg[rowperm[(c << 6) + l0 + j]];  // clamped <= 63
      d[j] = dd;
      if (dd > dmax) dmax = dd;
    }
    u64 full = (len >= 64) ? ~0ull : ((len == 0) ? 0 : ((1ull << len) - 1));
#pragma unroll
    for (int j = 0; j < 8; ++j) freeL[j] = full;
    u64 fC[8];
#pragma unroll
    for (int q = 0; q < 8; ++q) fC[q] = full;

    int2 cur[8], nxt[8];
#pragma unroll
    for (int j = 0; j < 8; ++j) cur[j] = esrc[base + l0 + j];  // slab 0
    for (int tt = 0; tt < dmax; ++tt) {
#pragma unroll
      for (int j = 0; j < 8; ++j) nxt[j] = esrc[base + ((tt + 1) << 6) + l0 + j];
#pragma unroll
      for (int j = 0; j < 8; ++j) {
        if (tt < d[j]) {
          int2 e = cur[j];
          int cls = (e.x >> 4) & 7;
          u64 fc = 0;
#pragma unroll
          for (int q = 0; q < 8; ++q) fc = (q == cls) ? fC[q] : fc;
          u64 avail = freeL[j] & fc;
          u64 pool = avail ? avail : freeL[j];   // nonzero: d[j] <= len
          u64 pick = pool & (~pool + 1);
          int slab = __builtin_ctzll(pick);
          freeL[j] &= ~pick;
          if (avail) {
#pragma unroll
            for (int q = 0; q < 8; ++q) if (q == cls) fC[q] &= ~pick;
          }
          edst[base + (slab << 6) + l0 + j] = e;
        }
      }
#pragma unroll
      for (int j = 0; j < 8; ++j) cur[j] = nxt[j];
    }
    // padding: every leftover (lane, slab) gets a class still free at that slab
#pragma unroll
    for (int j = 0; j < 8; ++j) {
      u64 rem = freeL[j];
      while (rem) {
        u64 pick = rem & (~rem + 1);
        rem &= rem - 1;
        int slab = __builtin_ctzll(pick);
        int cls = 0;
#pragma unroll
        for (int q = 7; q >= 0; --q) if (fC[q] & pick) cls = q;
#pragma unroll
        for (int q = 0; q < 8; ++q) if (q == cls) fC[q] &= ~pick;
        edst[base + (slab << 6) + l0 + j] = make_int2(cls << 4, 0);
      }
    }
  }
}

// ---- fused 16-step iteration + output projection epilogue ----

#define MIXL(acc, srcv) \
  asm("v_fma_mix_f32 %0, %1, %2, %0 op_sel_hi:[1,0,0]" : "+v"(acc) : "v"(srcv), "v"(w))
#define MIXH(acc, srcv) \
  asm("v_fma_mix_f32 %0, %1, %2, %0 op_sel:[1,0,0] op_sel_hi:[1,0,0]" : "+v"(acc) : "v"(srcv), "v"(w))

#define MIX16(lo, hi) \
  MIXL(a[0], lo.x);  MIXH(a[1], lo.x);  \
  MIXL(a[2], lo.y);  MIXH(a[3], lo.y);  \
  MIXL(a[4], lo.z);  MIXH(a[5], lo.z);  \
  MIXL(a[6], lo.w);  MIXH(a[7], lo.w);  \
  MIXL(a[8], hi.x);  MIXH(a[9], hi.x);  \
  MIXL(a[10], hi.y); MIXH(a[11], hi.y); \
  MIXL(a[12], hi.z); MIXH(a[13], hi.z); \
  MIXL(a[14], hi.w); MIXH(a[15], hi.w)

__global__ __launch_bounds__(THREADS, 4)
void fused_kernel(const int2* __restrict__ ell,
                  const int* __restrict__ chunk_off,
                  const int* __restrict__ chunk_len,
                  const int* __restrict__ rowperm,
                  const float* __restrict__ W,
                  const float* __restrict__ bvec,
                  float* __restrict__ out) {
  __shared__ __align__(16) h_t X[NN * CW];  // 128 KiB
  __shared__ float pe_lds[CW * PED];        // this block's 16 pe rows
  char* Xb = (char*)X;
  int c0 = blockIdx.x * CW;
  int tid = threadIdx.x;
  int wave = tid >> 6, lane = tid & 63;

  // hoist per-pass invariants (reloaded every step otherwise: __syncthreads
  // fence semantics force the compiler to re-read globals inside the k-loop)
  int baseB[PASSES], lenB[PASSES], djB[PASSES], xbW[PASSES];
#pragma unroll
  for (int pass = 0; pass < PASSES; ++pass) {
    // boustrophedon: each wave's 4 chunk ranks sum to a constant -> balanced
    int chunk = (pass << 4) + ((pass & 1) ? (15 - wave) : wave);
    baseB[pass] = chunk_off[chunk];
    lenB[pass] = chunk_len[chunk];   // even
    djB[pass] = rowperm[(chunk << 6) + lane] - c0;
    xbW[pass] = xp((chunk << 6) + lane);
  }

  // identity slice init (slot p holds row rowperm[p])
  for (int p = tid; p < NN; p += THREADS) {
    int dd = rowperm[p] - c0;
    h8 lo8, hi8;
#pragma unroll
    for (int j = 0; j < 8; ++j) {
      lo8[j] = (h_t)((dd == j) ? 1.0f : 0.0f);
      hi8[j] = (h_t)((dd == 8 + j) ? 1.0f : 0.0f);
    }
    int xb = xp(p);
    *reinterpret_cast<h8*>(Xb + xb) = lo8;
    *reinterpret_cast<h8*>(Xb + (xb ^ 16)) = hi8;
  }
  __syncthreads();

  for (int k = 0; k < PED; ++k) {
    h8 rlo[PASSES], rhi[PASSES];
#pragma unroll
    for (int pass = 0; pass < PASSES; ++pass) {
      int base = baseB[pass];
      int len = lenB[pass];
      float a[16];
#pragma unroll
      for (int j = 0; j < 16; ++j) a[j] = 0.f;
      const int2* ep = ell + base + lane;
      int2 e0 = ep[0];   // padding/slack entries always safe to read & apply
      int2 e1 = ep[64];
      int2 e2 = ep[128];
      int2 e3 = ep[192];
      int4 lo0 = *reinterpret_cast<const int4*>(Xb + e0.x);
      int4 hi0 = *reinterpret_cast<const int4*>(Xb + (e0.x ^ 16));
      for (int t = 0; t < len; t += 2) {    // unroll-2, 4-6-slab ELL prefetch
        int2 e4 = ep[256], e5 = ep[320];
        ep += 128;
        int4 lo1 = *reinterpret_cast<const int4*>(Xb + e1.x);
        int4 hi1 = *reinterpret_cast<const int4*>(Xb + (e1.x ^ 16));
        float w = __int_as_float(e0.y);
        MIX16(lo0, hi0);
        int4 nlo = *reinterpret_cast<const int4*>(Xb + e2.x);
        int4 nhi = *reinterpret_cast<const int4*>(Xb + (e2.x ^ 16));
        w = __int_as_float(e1.y);
        MIX16(lo1, hi1);
        e0 = e2; e1 = e3; e2 = e4; e3 = e5;
        lo0 = nlo; hi0 = nhi;
      }
      h8 plo, phi;
#pragma unroll
      for (int j = 0; j < 8; ++j) { plo[j] = (h_t)a[j]; phi[j] = (h_t)a[8 + j]; }
      rlo[pass] = plo; rhi[pass] = phi;
      int dj = djB[pass];
      if (dj >= 0 && dj < CW) {            // rare: diagonal entry, fp32 pre-rounding
        float dv = a[0];
#pragma unroll
        for (int j = 1; j < 16; ++j) dv = (dj == j) ? a[j] : dv;
        pe_lds[dj * PED + k] = dv;
      }
    }
    if (k != PED - 1) {                    // no write-back needed after last step
      __syncthreads();
#pragma unroll
      for (int pass = 0; pass < PASSES; ++pass) {
        int xb = xbW[pass];                 // balanced write granules
        *reinterpret_cast<h8*>(Xb + xb) = rlo[pass];
        *reinterpret_cast<h8*>(Xb + (xb ^ 16)) = rhi[pass];
      }
      __syncthreads();
    }
  }
  __syncthreads();  // pe_lds visibility

  // epilogue: out[c0+row, h] = sum_k pe_lds[row][k] * W[k][h] + b[h]
  {
    int h = tid & 127;
    int r0 = tid >> 7;   // 0..7, handles rows r0 and r0+8
    float wcol[PED];
#pragma unroll
    for (int kk = 0; kk < PED; ++kk) wcol[kk] = W[kk * HID + h];
    float bb = bvec[h];
#pragma unroll
    for (int half = 0; half < 2; ++half) {
      int row = r0 + (half << 3);
      float acc = bb;
#pragma unroll
      for (int kk = 0; kk < PED; ++kk) acc = fmaf(pe_lds[row * PED + kk], wcol[kk], acc);
      out[(size_t)(c0 + row) * HID + h] = acc;
    }
  }
}

extern "C" void kernel_launch(void* const* d_in, const int* in_sizes, int n_in,
                              void* d_out, int out_size, void* d_ws, size_t ws_size,
                              hipStream_t stream) {
  // inputs: 0=nodes (unused), 1=senders, 2=receivers, 3=W, 4=b
  const int* senders = (const int*)d_in[1];
  const int* receivers = (const int*)d_in[2];
  const float* W = (const float*)d_in[3];
  const float* bvec = (const float*)d_in[4];
  float* out = (float*)d_out;

  char* p = (char*)d_ws;
  int* outdeg = (int*)p;    p += (size_t)NN * 4;
  int* indeg = (int*)p;     p += (size_t)NN * 4;
  int* fillc = (int*)p;     p += (size_t)NN * 4;
  float* dinv = (float*)p;  p += (size_t)NN * 4;
  int* sortpos = (int*)p;   p += (size_t)NN * 4;
  int* rowperm = (int*)p;   p += (size_t)NN * 4;
  int* chunk_off = (int*)p; p += 128 * 4;
  int* chunk_len = (int*)p; p += 128 * 4;
  // ELL: worst case 64 chunks x 64 slabs x 64 lanes + prefetch tail
  size_t ell_slots = (size_t)NCHUNK * 64 * 64 + 2048;
  int2* esrc = (int2*)p;    p += ell_slots * sizeof(int2);
  int2* edst = (int2*)p;

  void* args[] = {
    (void*)&senders, (void*)&receivers, (void*)&dinv, (void*)&sortpos,
    (void*)&rowperm, (void*)&indeg, (void*)&outdeg, (void*)&fillc,
    (void*)&chunk_off, (void*)&chunk_len, (void*)&esrc, (void*)&edst
  };
  hipLaunchCooperativeKernel((void*)prep_coop, dim3(NE / 512), dim3(512), args, 0, stream);

  fused_kernel<<<NN / CW, THREADS, 0, stream>>>(edst, chunk_off, chunk_len, rowperm, W, bvec, out);
}